// Round 16
// baseline (1707.648 us; speedup 1.0000x reference)
//
#include <hip/hip_runtime.h>
#include <math.h>

#define LRELU 0.1f
#define SQRT_HALF 0.7071067811865476f

constexpr int T_LEN = 16384;

typedef __attribute__((ext_vector_type(8))) short short8;
typedef __attribute__((ext_vector_type(16))) float f32x16;

union U4S8 { uint4 v; short8 s8; unsigned short us[8]; };

__device__ inline void bsplit(float v, unsigned short& hi, unsigned short& lo) {
    unsigned u = __float_as_uint(v);
    unsigned rh = (u + 0x7FFFu + ((u >> 16) & 1u)) >> 16;
    float fh = __uint_as_float(rh << 16);
    float r = v - fh;
    unsigned u2 = __float_as_uint(r);
    unsigned rl = (u2 + 0x7FFFu + ((u2 >> 16) & 1u)) >> 16;
    hi = (unsigned short)rh; lo = (unsigned short)rl;
}
__device__ inline float b2f(unsigned short s) { return __uint_as_float(((unsigned)s) << 16); }

// 32x32 frag-tile uint4 index: Xf[n][tq 512][ic 8][lane 64]
// element j of lane l: ch = 16*ic + 4*(l>>5) + (j&3) + 8*(j>>2); t = 32*tq + (l&31)
__device__ inline size_t fidx32(int n, int tq, int ic, int l) {
    return ((size_t)((n << 9) + tq) * 8 + ic) * 64 + l;
}

__device__ inline float fast_gate(float g1, float g2) {
    float ax = fabsf(g1);
    float e = __expf(ax + ax);
    float th = 1.f - 2.f * __builtin_amdgcn_rcpf(e + 1.f);
    th = __uint_as_float(__float_as_uint(th) | (__float_as_uint(g1) & 0x80000000u));
    float sg = __builtin_amdgcn_rcpf(1.f + __expf(-g2));
    return th * sg;
}

// ======================= prep (32x32 A-operand packing) =======================
// Apk[li][ks 24][ct 8][h 2][lane 64][j 8]; k = ks*16 + 4*(l>>5)+(j&3)+8*(j>>2); tap=k>>7, i=k&127
// Spk[li][ks 8][ct 4][h 2][lane 64][j 8]; Opk1/Opk2 same as one Spk layer
__global__ void prep_w3(const float* __restrict__ wn_ws, const float* __restrict__ sk_ws,
                        const float* __restrict__ o1w, const float* __restrict__ o2w,
                        unsigned short* __restrict__ Apk, unsigned short* __restrict__ Spk,
                        unsigned short* __restrict__ Opk1, unsigned short* __restrict__ Opk2)
{
    int b = blockIdx.x, tid = threadIdx.x;
    if (b < 720) {                       // Apk: (li, ks)
        __shared__ float sl[256][17];
        int li = b / 24, ks = b % 24;
        int tap = ks >> 3, i0 = (ks & 7) * 16;
        for (int j = tid; j < 4096; j += 256) {
            int o = j >> 4, ii = j & 15;
            sl[o][ii] = wn_ws[((size_t)(li * 256 + o) * 128 + i0 + ii) * 3 + tap];
        }
        __syncthreads();
        size_t obase = ((size_t)(li * 24 + ks)) * 8192;
        for (int e = tid; e < 4096; e += 256) {
            int j = e & 7, l = (e >> 3) & 63, ct = e >> 9;
            int o = ct * 32 + (l & 31);
            int ii = 4 * (l >> 5) + (j & 3) + 8 * (j >> 2);
            unsigned short hi, lo; bsplit(sl[o][ii], hi, lo);
            Apk[obase + (size_t)ct * 1024 + l * 8 + j] = hi;
            Apk[obase + (size_t)ct * 1024 + 512 + l * 8 + j] = lo;
        }
    } else {                             // Spk (240) + Opk1 (8) + Opk2 (8)
        __shared__ float s2[128][17];
        int bb = b - 720;
        const float* src; unsigned short* dst; int ks2;
        if (bb < 240) { int li = bb / 8; ks2 = bb % 8; src = sk_ws + (size_t)li * 16384; dst = Spk + ((size_t)(li * 8 + ks2)) * 4096; }
        else if (bb < 248) { ks2 = bb - 240; src = o1w; dst = Opk1 + (size_t)ks2 * 4096; }
        else { ks2 = bb - 248; src = o2w; dst = Opk2 + (size_t)ks2 * 4096; }
        int i0 = ks2 * 16;
        for (int j = tid; j < 2048; j += 256) {
            int o = j >> 4, ii = j & 15;
            s2[o][ii] = src[(size_t)o * 128 + i0 + ii];
        }
        __syncthreads();
        for (int e = tid; e < 2048; e += 256) {
            int j = e & 7, l = (e >> 3) & 63, ct = e >> 9;
            int o = ct * 32 + (l & 31);
            int ii = 4 * (l >> 5) + (j & 3) + 8 * (j >> 2);
            unsigned short hi, lo; bsplit(s2[o][ii], hi, lo);
            dst[(size_t)ct * 1024 + l * 8 + j] = hi;
            dst[(size_t)ct * 1024 + 512 + l * 8 + j] = lo;
        }
    }
}

// ======================= front end (unchanged) =======================
__global__ void fe_in(const float* __restrict__ mel, const float* __restrict__ w,
                      const float* __restrict__ b, float* __restrict__ out)
{
    __shared__ float mc[80];
    int t = blockIdx.x, n = blockIdx.y, o = threadIdx.x;
    if (o < 80) mc[o] = mel[(n * 80 + o) * 64 + t];
    __syncthreads();
    float acc = b[o];
    #pragma unroll 8
    for (int i = 0; i < 80; i++) acc = fmaf(w[o * 80 + i], mc[i], acc);
    out[((size_t)n * 128 + o) * 64 + t] = acc;
}

__global__ void fe_pre(const float* __restrict__ in, float* __restrict__ out,
                       const float* __restrict__ w, const float* __restrict__ b, int d)
{
    __shared__ float col[3][128];
    int t = blockIdx.x, n = blockIdx.y, o = threadIdx.x;
    #pragma unroll
    for (int s = 0; s < 3; s++) {
        int tt = t + (s - 1) * d;
        col[s][o] = ((unsigned)tt < 64u) ? in[(n * 128 + o) * 64 + tt] : 0.f;
    }
    __syncthreads();
    float acc = b[o];
    const float* wo = w + o * 384;
    #pragma unroll 4
    for (int i = 0; i < 128; i++) {
        acc = fmaf(wo[i * 3 + 0], col[0][i], acc);
        acc = fmaf(wo[i * 3 + 1], col[1][i], acc);
        acc = fmaf(wo[i * 3 + 2], col[2][i], acc);
    }
    float y = acc > 0.f ? acc : LRELU * acc;
    out[(n * 128 + o) * 64 + t] = (y + in[(n * 128 + o) * 64 + t]) * SQRT_HALF;
}

__global__ __launch_bounds__(256, 4)
void fe_up3(const float* __restrict__ in, float* __restrict__ out,
            const float* __restrict__ w, const float* __restrict__ bias, int Lin)
{
    __shared__ float xs[128][16];
    const int n = blockIdx.y, qb = blockIdx.x * 16;
    const int tid = threadIdx.x;
    for (int j = tid; j < 2048; j += 256) {
        int i = j >> 4, qq = j & 15;
        xs[i][qq] = in[(size_t)(n * 128 + i) * Lin + qb + qq];
    }
    __syncthreads();
    const int o = tid & 127, qh = tid >> 7;
    float acc[8][4];
    #pragma unroll
    for (int q = 0; q < 8; q++)
        #pragma unroll
        for (int r = 0; r < 4; r++) acc[q][r] = 0.f;
    const float4* wo = (const float4*)(w + (size_t)o * 512);
    for (int i = 0; i < 128; i++) {
        float4 w4 = wo[i];
        #pragma unroll
        for (int q = 0; q < 8; q++) {
            float xv = xs[i][qh * 8 + q];
            acc[q][0] = fmaf(w4.w, xv, acc[q][0]);
            acc[q][1] = fmaf(w4.z, xv, acc[q][1]);
            acc[q][2] = fmaf(w4.y, xv, acc[q][2]);
            acc[q][3] = fmaf(w4.x, xv, acc[q][3]);
        }
    }
    float bo = bias[o];
    const int Lout = 4 * Lin;
    #pragma unroll
    for (int q = 0; q < 8; q++) {
        float4 v;
        float a0 = acc[q][0] + bo, a1 = acc[q][1] + bo, a2 = acc[q][2] + bo, a3 = acc[q][3] + bo;
        v.x = a0 > 0.f ? a0 : LRELU * a0;
        v.y = a1 > 0.f ? a1 : LRELU * a1;
        v.z = a2 > 0.f ? a2 : LRELU * a2;
        v.w = a3 > 0.f ? a3 : LRELU * a3;
        *(float4*)(out + (size_t)(n * 128 + o) * Lout + (size_t)(qb + qh * 8 + q) * 4) = v;
    }
}

// 16x repeat into 32x32 frag-tile bf16 hi/lo planes (block covers 1024 t = 32 tq)
__global__ void fe_repeat_f(const float* __restrict__ x1024,
                            uint4* __restrict__ Xh, uint4* __restrict__ Xl)
{
    __shared__ float sx[128][65];
    const int n = blockIdx.y, tbq = blockIdx.x;   // grid (16, 4)
    const int tid = threadIdx.x;
    for (int j = tid; j < 8192; j += 256) {
        int ch = j >> 6, col = j & 63;
        sx[ch][col] = x1024[(size_t)(n * 128 + ch) * 1024 + tbq * 64 + col];
    }
    __syncthreads();
    for (int m = tid; m < 16384; m += 256) {
        int l = m & 63, ic = (m >> 6) & 7, tqr = m >> 9;   // tqr in [0,32)
        int tl = tqr * 32 + (l & 31);                      // t_local in [0,1024)
        U4S8 ho, lo_;
        #pragma unroll
        for (int j = 0; j < 8; j++) {
            int ch = 16 * ic + 4 * (l >> 5) + (j & 3) + 8 * (j >> 2);
            unsigned short hi, lo; bsplit(sx[ch][tl >> 4], hi, lo);
            ho.us[j] = hi; lo_.us[j] = lo;
        }
        size_t gi = fidx32(n, tbq * 32 + tqr, ic, l);
        Xh[gi] = ho.v; Xl[gi] = lo_.v;
    }
}

// ======================= WaveNet layer v8 (32x32x16 MFMA) =======================
__global__ __launch_bounds__(256, 4)
void wn_layer(const uint4* __restrict__ Xh, const uint4* __restrict__ Xl,
              uint4* __restrict__ Yh, uint4* __restrict__ Yl,
              const unsigned short* __restrict__ Apk, const float* __restrict__ gb,
              const unsigned short* __restrict__ Spk, const float* __restrict__ skb, int dil)
{
    __shared__ __align__(16) uint4 S[2048];   // 32KB: [plane 2][tt 2][ic 8][lane 64]

    const int bxs = ((blockIdx.x & 7) << 5) | (blockIdx.x >> 3);  // XCD-contiguous spans
    const int n = blockIdx.y, tq0 = bxs * 2, t0 = tq0 * 32;
    const int tid = threadIdx.x, lane = tid & 63, w = tid >> 6;
    const bool direct = (dil >= 32);
    const int dq = dil >> 5;

    f32x16 acc[2][2];   // [ci: ct=w / ct=4+w][tt]
    #pragma unroll
    for (int ci = 0; ci < 2; ci++)
        #pragma unroll
        for (int tt = 0; tt < 2; tt++)
            #pragma unroll
            for (int r = 0; r < 16; r++) acc[ci][tt][r] = 0.f;

    const short8* ap = (const short8*)Apk;

    for (int s = 0; s < 3; s++) {
        if (!direct) {
            const int sh = (s - 1) * dil;
            __syncthreads();
            for (int j = tid; j < 2048; j += 256) {
                int p = j >> 10, r = j & 1023, l = r & 63, ic = (r >> 6) & 7, tt = r >> 9;
                int t = t0 + tt * 32 + (l & 31) + sh;
                uint4 v = make_uint4(0u, 0u, 0u, 0u);
                if ((unsigned)t < (unsigned)T_LEN)
                    v = (p ? Xl : Xh)[fidx32(n, t >> 5, ic, (l & 32) | (t & 31))];
                S[j] = v;
            }
            __syncthreads();
        }
        for (int k8 = 0; k8 < 8; k8++) {
            const int ks = s * 8 + k8;
            short8 Ah[2], Al[2];
            #pragma unroll
            for (int ci = 0; ci < 2; ci++) {
                int ib = ((ks * 8 + (w + 4 * ci)) * 2) * 64 + lane;
                Ah[ci] = ap[ib];
                Al[ci] = ap[ib + 64];
            }
            #pragma unroll
            for (int tt = 0; tt < 2; tt++) {
                U4S8 bh, bl;
                bool ok = true;
                if (direct) {
                    int tq = tq0 + tt + (s - 1) * dq;
                    ok = ((unsigned)tq < 512u);
                    if (ok) {
                        size_t gi = fidx32(n, tq, k8, lane);
                        bh.v = Xh[gi]; bl.v = Xl[gi];
                    }
                } else {
                    bh.v = S[(tt * 8 + k8) * 64 + lane];
                    bl.v = S[1024 + (tt * 8 + k8) * 64 + lane];
                }
                if (ok) {
                    #pragma unroll
                    for (int ci = 0; ci < 2; ci++) {
                        acc[ci][tt] = __builtin_amdgcn_mfma_f32_32x32x16_bf16(Ah[ci], bh.s8, acc[ci][tt], 0, 0, 0);
                        acc[ci][tt] = __builtin_amdgcn_mfma_f32_32x32x16_bf16(Al[ci], bh.s8, acc[ci][tt], 0, 0, 0);
                        acc[ci][tt] = __builtin_amdgcn_mfma_f32_32x32x16_bf16(Ah[ci], bl.s8, acc[ci][tt], 0, 0, 0);
                    }
                }
            }
        }
    }
    if (!direct) __syncthreads();

    // ---- gating: row(reg,lane) = (reg&3)+8*(reg>>2)+4*(lane>>5); reg=g2*8+jj -> slot (ic=2w+g2, j=jj) of OWN lane
    const int rsel = 4 * (lane >> 5);
    float4 btv[4], bsv[4];
    #pragma unroll
    for (int rg = 0; rg < 4; rg++) {
        btv[rg] = *(const float4*)(gb + 32 * w + rg * 8 + rsel);
        bsv[rg] = *(const float4*)(gb + 128 + 32 * w + rg * 8 + rsel);
    }
    #pragma unroll
    for (int tt = 0; tt < 2; tt++) {
        #pragma unroll
        for (int g2 = 0; g2 < 2; g2++) {
            U4S8 h4, l4;
            #pragma unroll
            for (int jj = 0; jj < 8; jj++) {
                int reg = g2 * 8 + jj;
                int rg = reg >> 2, e = reg & 3;
                float bt = (e == 0) ? btv[rg].x : (e == 1) ? btv[rg].y : (e == 2) ? btv[rg].z : btv[rg].w;
                float bs = (e == 0) ? bsv[rg].x : (e == 1) ? bsv[rg].y : (e == 2) ? bsv[rg].z : bsv[rg].w;
                float gv = fast_gate(acc[0][tt][reg] + bt, acc[1][tt][reg] + bs);
                unsigned short hi, lo; bsplit(gv, hi, lo);
                h4.us[jj] = hi; l4.us[jj] = lo;
            }
            S[(tt * 8 + 2 * w + g2) * 64 + lane] = h4.v;
            S[1024 + (tt * 8 + 2 * w + g2) * 64 + lane] = l4.v;
        }
    }
    __syncthreads();

    // ---- skip 1x1 GEMM: out ch-tile = w (32 ch), K=128 in 8 k-steps ----
    f32x16 acc2[2];
    #pragma unroll
    for (int tt = 0; tt < 2; tt++)
        #pragma unroll
        for (int r = 0; r < 16; r++) acc2[tt][r] = 0.f;
    const short8* sp = (const short8*)Spk;
    #pragma unroll
    for (int ks = 0; ks < 8; ks++) {
        int ib = ((ks * 4 + w) * 2) * 64 + lane;
        short8 A2h = sp[ib];
        short8 A2l = sp[ib + 64];
        #pragma unroll
        for (int tt = 0; tt < 2; tt++) {
            U4S8 bh, bl;
            bh.v = S[(tt * 8 + ks) * 64 + lane];
            bl.v = S[1024 + (tt * 8 + ks) * 64 + lane];
            acc2[tt] = __builtin_amdgcn_mfma_f32_32x32x16_bf16(A2h, bh.s8, acc2[tt], 0, 0, 0);
            acc2[tt] = __builtin_amdgcn_mfma_f32_32x32x16_bf16(A2l, bh.s8, acc2[tt], 0, 0, 0);
            acc2[tt] = __builtin_amdgcn_mfma_f32_32x32x16_bf16(A2h, bl.s8, acc2[tt], 0, 0, 0);
        }
    }

    // ---- epilogue: y = s + bias + x_center; frag-coalesced write ----
    float4 skv[4];
    #pragma unroll
    for (int rg = 0; rg < 4; rg++)
        skv[rg] = *(const float4*)(skb + 32 * w + rg * 8 + rsel);
    #pragma unroll
    for (int tt = 0; tt < 2; tt++) {
        #pragma unroll
        for (int g2 = 0; g2 < 2; g2++) {
            size_t gi = fidx32(n, tq0 + tt, 2 * w + g2, lane);
            U4S8 xh, xl, oh, ol;
            xh.v = Xh[gi]; xl.v = Xl[gi];
            #pragma unroll
            for (int jj = 0; jj < 8; jj++) {
                int reg = g2 * 8 + jj;
                int rg = reg >> 2, e = reg & 3;
                float bo = (e == 0) ? skv[rg].x : (e == 1) ? skv[rg].y : (e == 2) ? skv[rg].z : skv[rg].w;
                float xin = b2f(xh.us[jj]) + b2f(xl.us[jj]);
                float sv = acc2[tt][reg] + bo;
                unsigned short hi, lo; bsplit(sv + xin, hi, lo);
                oh.us[jj] = hi; ol.us[jj] = lo;
            }
            Yh[gi] = oh.v; Yl[gi] = ol.v;
        }
    }
}

// ======================= fused output stack (32x32) =======================
__global__ __launch_bounds__(256, 2)
void os_fused(const uint4* __restrict__ Fh, const uint4* __restrict__ Fl,
              const uint4* __restrict__ Ih, const uint4* __restrict__ Il,
              const unsigned short* __restrict__ Opk1, const float* __restrict__ o1b,
              const unsigned short* __restrict__ Opk2, const float* __restrict__ o2b,
              const float* __restrict__ o3w, const float* __restrict__ o3b,
              float* __restrict__ out)
{
    __shared__ __align__(16) uint4 SA[2048];   // frag pairs; later reused as f32 [64][128] xor tile
    __shared__ __align__(16) uint4 SB[2048];
    const int n = blockIdx.y, tq0 = blockIdx.x * 2, t0 = tq0 * 32;
    const int tid = threadIdx.x, lane = tid & 63, w = tid >> 6;
    const int rsel = 4 * (lane >> 5);
    char* ldsA = (char*)SA;

    // P1: relu(xfin - xinit) -> frag pairs in SA
    for (int j = tid; j < 1024; j += 256) {
        int l = j & 63, ic = (j >> 6) & 7, tt = j >> 9;
        size_t gi = fidx32(n, tq0 + tt, ic, l);
        U4S8 fh, fl, ih, il, ho, lo_;
        fh.v = Fh[gi]; fl.v = Fl[gi]; ih.v = Ih[gi]; il.v = Il[gi];
        #pragma unroll
        for (int e = 0; e < 8; e++) {
            float d = (b2f(fh.us[e]) + b2f(fl.us[e])) - (b2f(ih.us[e]) + b2f(il.us[e]));
            d = fmaxf(d, 0.f);
            unsigned short hi, lo; bsplit(d, hi, lo);
            ho.us[e] = hi; lo_.us[e] = lo;
        }
        SA[j] = ho.v; SA[1024 + j] = lo_.v;
    }
    __syncthreads();

    // P2: GEMM1 -> relu -> frag pairs in SB
    {
        f32x16 acc[2];
        #pragma unroll
        for (int tt = 0; tt < 2; tt++)
            #pragma unroll
            for (int r = 0; r < 16; r++) acc[tt][r] = 0.f;
        const short8* op = (const short8*)Opk1;
        #pragma unroll
        for (int ks = 0; ks < 8; ks++) {
            int ib = ((ks * 4 + w) * 2) * 64 + lane;
            short8 Ah = op[ib], Al = op[ib + 64];
            #pragma unroll
            for (int tt = 0; tt < 2; tt++) {
                U4S8 bh, bl;
                bh.v = SA[(tt * 8 + ks) * 64 + lane];
                bl.v = SA[1024 + (tt * 8 + ks) * 64 + lane];
                acc[tt] = __builtin_amdgcn_mfma_f32_32x32x16_bf16(Ah, bh.s8, acc[tt], 0, 0, 0);
                acc[tt] = __builtin_amdgcn_mfma_f32_32x32x16_bf16(Al, bh.s8, acc[tt], 0, 0, 0);
                acc[tt] = __builtin_amdgcn_mfma_f32_32x32x16_bf16(Ah, bl.s8, acc[tt], 0, 0, 0);
            }
        }
        float4 b1v[4];
        #pragma unroll
        for (int rg = 0; rg < 4; rg++)
            b1v[rg] = *(const float4*)(o1b + 32 * w + rg * 8 + rsel);
        #pragma unroll
        for (int tt = 0; tt < 2; tt++)
            #pragma unroll
            for (int g2 = 0; g2 < 2; g2++) {
                U4S8 h4, l4;
                #pragma unroll
                for (int jj = 0; jj < 8; jj++) {
                    int reg = g2 * 8 + jj;
                    int rg = reg >> 2, e = reg & 3;
                    float bo = (e == 0) ? b1v[rg].x : (e == 1) ? b1v[rg].y : (e == 2) ? b1v[rg].z : b1v[rg].w;
                    float v = fmaxf(acc[tt][reg] + bo, 0.f);
                    unsigned short hi, lo; bsplit(v, hi, lo);
                    h4.us[jj] = hi; l4.us[jj] = lo;
                }
                SB[(tt * 8 + 2 * w + g2) * 64 + lane] = h4.v;
                SB[1024 + (tt * 8 + 2 * w + g2) * 64 + lane] = l4.v;
            }
    }
    __syncthreads();

    // P3: GEMM2 -> relu -> f32 xor tile in SA
    {
        f32x16 acc[2];
        #pragma unroll
        for (int tt = 0; tt < 2; tt++)
            #pragma unroll
            for (int r = 0; r < 16; r++) acc[tt][r] = 0.f;
        const short8* op = (const short8*)Opk2;
        #pragma unroll
        for (int ks = 0; ks < 8; ks++) {
            int ib = ((ks * 4 + w) * 2) * 64 + lane;
            short8 Ah = op[ib], Al = op[ib + 64];
            #pragma unroll
            for (int tt = 0; tt < 2; tt++) {
                U4S8 bh, bl;
                bh.v = SB[(tt * 8 + ks) * 64 + lane];
                bl.v = SB[1024 + (tt * 8 + ks) * 64 + lane];
                acc[tt] = __builtin_amdgcn_mfma_f32_32x32x16_bf16(Ah, bh.s8, acc[tt], 0, 0, 0);
                acc[tt] = __builtin_amdgcn_mfma_f32_32x32x16_bf16(Al, bh.s8, acc[tt], 0, 0, 0);
                acc[tt] = __builtin_amdgcn_mfma_f32_32x32x16_bf16(Ah, bl.s8, acc[tt], 0, 0, 0);
            }
        }
        float4 b2v[4];
        #pragma unroll
        for (int rg = 0; rg < 4; rg++)
            b2v[rg] = *(const float4*)(o2b + 32 * w + rg * 8 + rsel);
        __syncthreads();   // all SA frag reads (P2) done -> reuse SA as f32 tile
        #pragma unroll
        for (int tt = 0; tt < 2; tt++) {
            int tl = tt * 32 + (lane & 31);
            int swz = (tl & 7) << 4;
            #pragma unroll
            for (int rg = 0; rg < 4; rg++) {
                int ch0 = 32 * w + rg * 8 + rsel;
                float4 v;
                v.x = fmaxf(acc[tt][rg * 4 + 0] + b2v[rg].x, 0.f);
                v.y = fmaxf(acc[tt][rg * 4 + 1] + b2v[rg].y, 0.f);
                v.z = fmaxf(acc[tt][rg * 4 + 2] + b2v[rg].z, 0.f);
                v.w = fmaxf(acc[tt][rg * 4 + 3] + b2v[rg].w, 0.f);
                *(float4*)(ldsA + tl * 512 + ((ch0 * 4) ^ swz)) = v;
            }
        }
    }
    __syncthreads();

    // P4: final 1-ch conv + tanh
    {
        const int t_loc = tid >> 2, qq = tid & 3;
        const int row = t_loc, swz = (row & 7) << 4;
        float a = 0.f;
        #pragma unroll
        for (int cc = 0; cc < 8; cc++) {
            int ch = qq * 32 + cc * 4;
            float4 v = *(const float4*)(ldsA + row * 512 + ((ch * 4) ^ swz));
            a += o3w[ch] * v.x + o3w[ch + 1] * v.y + o3w[ch + 2] * v.z + o3w[ch + 3] * v.w;
        }
        a += __shfl_xor(a, 1);
        a += __shfl_xor(a, 2);
        if (qq == 0) out[(size_t)n * T_LEN + t0 + t_loc] = tanhf(a + o3b[0]);
    }
}

// ======================= launch =======================
extern "C" void kernel_launch(void* const* d_in, const int* in_sizes, int n_in,
                              void* d_out, int out_size, void* d_ws, size_t ws_size,
                              hipStream_t stream)
{
    (void)in_sizes; (void)n_in; (void)out_size; (void)ws_size;
    const float* mel    = (const float*)d_in[0];
    const float* in_w   = (const float*)d_in[1];
    const float* in_b   = (const float*)d_in[2];
    const float* pre_w  = (const float*)d_in[3];
    const float* pre_b  = (const float*)d_in[4];
    const float* up1_w  = (const float*)d_in[5];
    const float* up1_b  = (const float*)d_in[6];
    const float* up2_w  = (const float*)d_in[7];
    const float* up2_b  = (const float*)d_in[8];
    const float* wn_wsp = (const float*)d_in[9];
    const float* wn_bs  = (const float*)d_in[10];
    const float* sk_wsp = (const float*)d_in[11];
    const float* sk_bs  = (const float*)d_in[12];
    const float* o1w = (const float*)d_in[13];
    const float* o1b = (const float*)d_in[14];
    const float* o2w = (const float*)d_in[15];
    const float* o2b = (const float*)d_in[16];
    const float* o3w = (const float*)d_in[17];
    const float* o3b = (const float*)d_in[18];

    // each bf16 plane: 8,388,608 elems = 16,777,216 BYTES
    char* base = (char*)d_ws;
    uint4* XAh = (uint4*)(base);
    uint4* XAl = (uint4*)(base + 16777216);
    uint4* XBh = (uint4*)(base + 33554432);
    uint4* XBl = (uint4*)(base + 50331648);
    uint4* XCh = (uint4*)(base + 67108864);
    uint4* XCl = (uint4*)(base + 83886080);
    unsigned short* Apk = (unsigned short*)(base + 100663296);   // 11,796,480 B
    unsigned short* Spk = (unsigned short*)(base + 112459776);   //  1,966,080 B
    unsigned short* Opk1 = (unsigned short*)(base + 114425856);  //     65,536 B
    unsigned short* Opk2 = (unsigned short*)(base + 114491392);  //     65,536 B
    float* a64   = (float*)(base + 114556928);
    float* b64   = (float*)(base + 114688000);
    float* x256  = (float*)(base + 114819072);
    float* x1024 = (float*)(base + 115343360);

    prep_w3<<<976, 256, 0, stream>>>(wn_wsp, sk_wsp, o1w, o2w, Apk, Spk, Opk1, Opk2);

    fe_in<<<dim3(64, 4), 128, 0, stream>>>(mel, in_w, in_b, a64);
    fe_pre<<<dim3(64, 4), 128, 0, stream>>>(a64, b64, pre_w + 0 * 49152, pre_b + 0 * 128, 1);
    fe_pre<<<dim3(64, 4), 128, 0, stream>>>(b64, a64, pre_w + 1 * 49152, pre_b + 1 * 128, 2);
    fe_pre<<<dim3(64, 4), 128, 0, stream>>>(a64, b64, pre_w + 2 * 49152, pre_b + 2 * 128, 4);
    fe_pre<<<dim3(64, 4), 128, 0, stream>>>(b64, a64, pre_w + 3 * 49152, pre_b + 3 * 128, 8);
    fe_pre<<<dim3(64, 4), 128, 0, stream>>>(a64, b64, pre_w + 4 * 49152, pre_b + 4 * 128, 16);
    fe_up3<<<dim3(4, 4), 256, 0, stream>>>(b64, x256, up1_w, up1_b, 64);
    fe_up3<<<dim3(16, 4), 256, 0, stream>>>(x256, x1024, up2_w, up2_b, 256);
    fe_repeat_f<<<dim3(16, 4), 256, 0, stream>>>(x1024, XAh, XAl);

    for (int li = 0; li < 30; li++) {
        int d = 1 << (li % 10);
        const uint4 *ih, *il; uint4 *oh, *ol;
        if (li == 0)      { ih = XAh; il = XAl; oh = XBh; ol = XBl; }
        else if (li & 1)  { ih = XBh; il = XBl; oh = XCh; ol = XCl; }
        else              { ih = XCh; il = XCl; oh = XBh; ol = XBl; }
        wn_layer<<<dim3(T_LEN / 64, 4), 256, 0, stream>>>(
            ih, il, oh, ol,
            Apk + (size_t)li * 196608, wn_bs + li * 256,
            Spk + (size_t)li * 32768, sk_bs + li * 128, d);
    }

    // skips = x_final - x_init
    os_fused<<<dim3(T_LEN / 64, 4), 256, 0, stream>>>(
        XCh, XCl, XAh, XAl, Opk1, o1b, Opk2, o2b, o3w, o3b, (float*)d_out);
}

// Round 17
// 1530.909 us; speedup vs baseline: 1.1154x; 1.1154x over previous
//
#include <hip/hip_runtime.h>
#include <math.h>

#define LRELU 0.1f
#define SQRT_HALF 0.7071067811865476f

constexpr int T_LEN = 16384;

typedef __attribute__((ext_vector_type(8))) short short8;
typedef __attribute__((ext_vector_type(4))) float f32x4;

union U4S8 { uint4 v; short8 s8; unsigned short us[8]; };

__device__ inline void bsplit(float v, unsigned short& hi, unsigned short& lo) {
    unsigned u = __float_as_uint(v);
    unsigned rh = (u + 0x7FFFu + ((u >> 16) & 1u)) >> 16;
    float fh = __uint_as_float(rh << 16);
    float r = v - fh;
    unsigned u2 = __float_as_uint(r);
    unsigned rl = (u2 + 0x7FFFu + ((u2 >> 16) & 1u)) >> 16;
    hi = (unsigned short)rh; lo = (unsigned short)rl;
}
__device__ inline float b2f(unsigned short s) { return __uint_as_float(((unsigned)s) << 16); }

// frag-tile uint4 index: Xf[n][tb][c][lane] (16B per lane)
__device__ inline size_t fidx(int n, int tb, int c, int l) {
    return ((size_t)((n << 10) + tb) * 4 + c) * 64 + l;
}

__device__ inline float fast_gate(float g1, float g2) {
    float ax = fabsf(g1);
    float e = __expf(ax + ax);
    float th = 1.f - 2.f * __builtin_amdgcn_rcpf(e + 1.f);
    th = __uint_as_float(__float_as_uint(th) | (__float_as_uint(g1) & 0x80000000u));
    float sg = __builtin_amdgcn_rcpf(1.f + __expf(-g2));
    return th * sg;
}

// ======================= prep =======================
__global__ void prep_w3(const float* __restrict__ wn_ws, const float* __restrict__ sk_ws,
                        const float* __restrict__ o1w, const float* __restrict__ o2w,
                        unsigned short* __restrict__ Apk, unsigned short* __restrict__ Spk,
                        unsigned short* __restrict__ Opk1, unsigned short* __restrict__ Opk2)
{
    int b = blockIdx.x, tid = threadIdx.x;
    if (b < 360) {
        __shared__ float sl[256][32];
        int li = b / 12, ks = b % 12;
        int tap = ks >> 2, i0 = (ks & 3) * 32;
        for (int j = tid; j < 8192; j += 256) {
            int o = j >> 5, ii = j & 31;
            sl[o][ii] = wn_ws[((size_t)(li * 256 + o) * 128 + i0 + ii) * 3 + tap];
        }
        __syncthreads();
        size_t obase = ((size_t)(li * 12 + ks)) * 16384;
        for (int e = tid; e < 8192; e += 256) {
            int j = e & 7, l = (e >> 3) & 63, m16 = e >> 9;
            int o = m16 * 16 + (l & 15);
            int ii = 4 * (l >> 4) + (j & 3) + 16 * (j >> 2);
            unsigned short hi, lo; bsplit(sl[o][ii], hi, lo);
            Apk[obase + (size_t)m16 * 1024 + l * 8 + j] = hi;
            Apk[obase + (size_t)m16 * 1024 + 512 + l * 8 + j] = lo;
        }
    } else {
        __shared__ float s2[128][32];
        int bb = b - 360;
        const float* src; unsigned short* dst; int ks2;
        if (bb < 120) { int li = bb / 4; ks2 = bb % 4; src = sk_ws + (size_t)li * 16384; dst = Spk + ((size_t)(li * 4 + ks2)) * 8192; }
        else if (bb < 124) { ks2 = bb - 120; src = o1w; dst = Opk1 + (size_t)ks2 * 8192; }
        else { ks2 = bb - 124; src = o2w; dst = Opk2 + (size_t)ks2 * 8192; }
        int i0 = ks2 * 32;
        for (int j = tid; j < 4096; j += 256) {
            int o = j >> 5, ii = j & 31;
            s2[o][ii] = src[(size_t)o * 128 + i0 + ii];
        }
        __syncthreads();
        for (int e = tid; e < 4096; e += 256) {
            int j = e & 7, l = (e >> 3) & 63, m8 = e >> 9;
            int o = m8 * 16 + (l & 15);
            int ii = 4 * (l >> 4) + (j & 3) + 16 * (j >> 2);
            unsigned short hi, lo; bsplit(s2[o][ii], hi, lo);
            dst[(size_t)m8 * 1024 + l * 8 + j] = hi;
            dst[(size_t)m8 * 1024 + 512 + l * 8 + j] = lo;
        }
    }
}

// ======================= front end =======================
__global__ void fe_in(const float* __restrict__ mel, const float* __restrict__ w,
                      const float* __restrict__ b, float* __restrict__ out)
{
    __shared__ float mc[80];
    int t = blockIdx.x, n = blockIdx.y, o = threadIdx.x;
    if (o < 80) mc[o] = mel[(n * 80 + o) * 64 + t];
    __syncthreads();
    float acc = b[o];
    #pragma unroll 8
    for (int i = 0; i < 80; i++) acc = fmaf(w[o * 80 + i], mc[i], acc);
    out[((size_t)n * 128 + o) * 64 + t] = acc;
}

__global__ void fe_pre(const float* __restrict__ in, float* __restrict__ out,
                       const float* __restrict__ w, const float* __restrict__ b, int d)
{
    __shared__ float col[3][128];
    int t = blockIdx.x, n = blockIdx.y, o = threadIdx.x;
    #pragma unroll
    for (int s = 0; s < 3; s++) {
        int tt = t + (s - 1) * d;
        col[s][o] = ((unsigned)tt < 64u) ? in[(n * 128 + o) * 64 + tt] : 0.f;
    }
    __syncthreads();
    float acc = b[o];
    const float* wo = w + o * 384;
    #pragma unroll 4
    for (int i = 0; i < 128; i++) {
        acc = fmaf(wo[i * 3 + 0], col[0][i], acc);
        acc = fmaf(wo[i * 3 + 1], col[1][i], acc);
        acc = fmaf(wo[i * 3 + 2], col[2][i], acc);
    }
    float y = acc > 0.f ? acc : LRELU * acc;
    out[(n * 128 + o) * 64 + t] = (y + in[(n * 128 + o) * 64 + t]) * SQRT_HALF;
}

__global__ __launch_bounds__(256, 4)
void fe_up3(const float* __restrict__ in, float* __restrict__ out,
            const float* __restrict__ w, const float* __restrict__ bias, int Lin)
{
    __shared__ float xs[128][16];
    const int n = blockIdx.y, qb = blockIdx.x * 16;
    const int tid = threadIdx.x;
    for (int j = tid; j < 2048; j += 256) {
        int i = j >> 4, qq = j & 15;
        xs[i][qq] = in[(size_t)(n * 128 + i) * Lin + qb + qq];
    }
    __syncthreads();
    const int o = tid & 127, qh = tid >> 7;
    float acc[8][4];
    #pragma unroll
    for (int q = 0; q < 8; q++)
        #pragma unroll
        for (int r = 0; r < 4; r++) acc[q][r] = 0.f;
    const float4* wo = (const float4*)(w + (size_t)o * 512);
    for (int i = 0; i < 128; i++) {
        float4 w4 = wo[i];
        #pragma unroll
        for (int q = 0; q < 8; q++) {
            float xv = xs[i][qh * 8 + q];
            acc[q][0] = fmaf(w4.w, xv, acc[q][0]);
            acc[q][1] = fmaf(w4.z, xv, acc[q][1]);
            acc[q][2] = fmaf(w4.y, xv, acc[q][2]);
            acc[q][3] = fmaf(w4.x, xv, acc[q][3]);
        }
    }
    float bo = bias[o];
    const int Lout = 4 * Lin;
    #pragma unroll
    for (int q = 0; q < 8; q++) {
        float4 v;
        float a0 = acc[q][0] + bo, a1 = acc[q][1] + bo, a2 = acc[q][2] + bo, a3 = acc[q][3] + bo;
        v.x = a0 > 0.f ? a0 : LRELU * a0;
        v.y = a1 > 0.f ? a1 : LRELU * a1;
        v.z = a2 > 0.f ? a2 : LRELU * a2;
        v.w = a3 > 0.f ? a3 : LRELU * a3;
        *(float4*)(out + (size_t)(n * 128 + o) * Lout + (size_t)(qb + qh * 8 + q) * 4) = v;
    }
}

__global__ void fe_repeat_f(const float* __restrict__ x1024,
                            uint4* __restrict__ Xh, uint4* __restrict__ Xl)
{
    __shared__ float sx[128][65];
    const int n = blockIdx.y, tbq = blockIdx.x;
    const int tid = threadIdx.x;
    for (int j = tid; j < 8192; j += 256) {
        int ch = j >> 6, col = j & 63;
        sx[ch][col] = x1024[(size_t)(n * 128 + ch) * 1024 + tbq * 64 + col];
    }
    __syncthreads();
    for (int m = tid; m < 16384; m += 256) {
        int l = m & 63, c = (m >> 6) & 3, tbr = m >> 8;
        U4S8 ho, lo_;
        #pragma unroll
        for (int j = 0; j < 8; j++) {
            int ch = 32 * c + 4 * (l >> 4) + (j & 3) + 16 * (j >> 2);
            unsigned short hi, lo; bsplit(sx[ch][tbr], hi, lo);
            ho.us[j] = hi; lo_.us[j] = lo;
        }
        size_t gi = fidx(n, tbq * 64 + tbr, c, l);
        Xh[gi] = ho.v; Xl[gi] = lo_.v;
    }
}

// ======================= WaveNet layer v5.1 (R9 structure + XCD swizzle) =======================
__global__ __launch_bounds__(256, 4)
void wn_layer(const uint4* __restrict__ Xh, const uint4* __restrict__ Xl,
              uint4* __restrict__ Yh, uint4* __restrict__ Yl,
              const unsigned short* __restrict__ Apk, const float* __restrict__ gb,
              const unsigned short* __restrict__ Spk, const float* __restrict__ skb, int dil)
{
    __shared__ __align__(16) uint4 S[2048];   // 32KB: [plane][nf][c][lane]

    // XCD-aware swizzle (256 x-blocks, 8 XCDs): each XCD owns a contiguous 128-tile span
    const int bxs = ((blockIdx.x & 7) << 5) | (blockIdx.x >> 3);
    const int n = blockIdx.y, tb0 = bxs * 4, t0 = tb0 * 16;
    const int tid = threadIdx.x, lane = tid & 63, wid = tid >> 6;
    const bool direct = (dil >= 16);
    const int dq = dil >> 4;

    f32x4 acc[4][4];
    const f32x4 z4 = {0.f, 0.f, 0.f, 0.f};
    #pragma unroll
    for (int mf = 0; mf < 4; mf++)
        #pragma unroll
        for (int nf = 0; nf < 4; nf++) acc[mf][nf] = z4;

    const short8* ap = (const short8*)Apk;
    const int m16c[4] = {2 * wid, 2 * wid + 1, 8 + 2 * wid, 9 + 2 * wid};

    for (int s = 0; s < 3; s++) {
        if (!direct) {
            const int sh = (s - 1) * dil;
            __syncthreads();
            for (int j = tid; j < 1024; j += 256) {
                int l = j & 63, c = (j >> 6) & 3, nf = j >> 8;
                int t = t0 + nf * 16 + (l & 15) + sh;
                uint4 vh = make_uint4(0u, 0u, 0u, 0u), vl = vh;
                if ((unsigned)t < (unsigned)T_LEN) {
                    size_t gi = fidx(n, t >> 4, c, (l & 48) | (t & 15));
                    vh = Xh[gi]; vl = Xl[gi];
                }
                S[j] = vh; S[1024 + j] = vl;
            }
            __syncthreads();
        }
        const int tbS = tb0 + (s - 1) * dq;
        for (int c = 0; c < 4; c++) {
            const int ks = s * 4 + c;
            short8 Ah[4], Al[4];
            #pragma unroll
            for (int mf = 0; mf < 4; mf++) {
                int ib = (ks * 16 + m16c[mf]) * 128 + lane;
                Ah[mf] = ap[ib];
                Al[mf] = ap[ib + 64];
            }
            #pragma unroll
            for (int nf = 0; nf < 4; nf++) {
                U4S8 bh, bl;
                bool ok = true;
                if (direct) {
                    int tb = tbS + nf;
                    ok = ((unsigned)tb < 1024u);
                    if (ok) {
                        size_t gi = fidx(n, tb, c, lane);
                        bh.v = Xh[gi]; bl.v = Xl[gi];
                    }
                } else {
                    bh.v = S[(nf * 4 + c) * 64 + lane];
                    bl.v = S[1024 + (nf * 4 + c) * 64 + lane];
                }
                if (ok) {
                    #pragma unroll
                    for (int mf = 0; mf < 4; mf++) {
                        acc[mf][nf] = __builtin_amdgcn_mfma_f32_16x16x32_bf16(Ah[mf], bh.s8, acc[mf][nf], 0, 0, 0);
                        acc[mf][nf] = __builtin_amdgcn_mfma_f32_16x16x32_bf16(Al[mf], bh.s8, acc[mf][nf], 0, 0, 0);
                        acc[mf][nf] = __builtin_amdgcn_mfma_f32_16x16x32_bf16(Ah[mf], bl.s8, acc[mf][nf], 0, 0, 0);
                    }
                }
            }
        }
    }
    if (!direct) __syncthreads();

    // ---- gating -> S in frag layout (c = wid, j = r + 4*mf2) ----
    const int cb = 4 * (lane >> 4);
    float bt[2][4], bsg[2][4];
    #pragma unroll
    for (int mf2 = 0; mf2 < 2; mf2++)
        #pragma unroll
        for (int r = 0; r < 4; r++) {
            int ch = (2 * wid + mf2) * 16 + cb + r;
            bt[mf2][r] = gb[ch];
            bsg[mf2][r] = gb[128 + ch];
        }
    #pragma unroll
    for (int nf = 0; nf < 4; nf++) {
        U4S8 h4, l4;
        #pragma unroll
        for (int mf2 = 0; mf2 < 2; mf2++)
            #pragma unroll
            for (int r = 0; r < 4; r++) {
                float g1 = acc[mf2][nf][r] + bt[mf2][r];
                float g2 = acc[mf2 + 2][nf][r] + bsg[mf2][r];
                float gv = fast_gate(g1, g2);
                unsigned short hi, lo; bsplit(gv, hi, lo);
                h4.us[mf2 * 4 + r] = hi;
                l4.us[mf2 * 4 + r] = lo;
            }
        S[(nf * 4 + wid) * 64 + lane] = h4.v;
        S[1024 + (nf * 4 + wid) * 64 + lane] = l4.v;
    }
    __syncthreads();

    // ---- skip 1x1 GEMM ----
    f32x4 acc2[2][4];
    #pragma unroll
    for (int mf2 = 0; mf2 < 2; mf2++)
        #pragma unroll
        for (int nf = 0; nf < 4; nf++) acc2[mf2][nf] = z4;
    const short8* sp = (const short8*)Spk;
    #pragma unroll
    for (int c = 0; c < 4; c++) {
        short8 A2h[2], A2l[2];
        #pragma unroll
        for (int mf2 = 0; mf2 < 2; mf2++) {
            int ib = (c * 8 + 2 * wid + mf2) * 128 + lane;
            A2h[mf2] = sp[ib];
            A2l[mf2] = sp[ib + 64];
        }
        #pragma unroll
        for (int nf = 0; nf < 4; nf++) {
            U4S8 bh, bl;
            bh.v = S[(nf * 4 + c) * 64 + lane];
            bl.v = S[1024 + (nf * 4 + c) * 64 + lane];
            #pragma unroll
            for (int mf2 = 0; mf2 < 2; mf2++) {
                acc2[mf2][nf] = __builtin_amdgcn_mfma_f32_16x16x32_bf16(A2h[mf2], bh.s8, acc2[mf2][nf], 0, 0, 0);
                acc2[mf2][nf] = __builtin_amdgcn_mfma_f32_16x16x32_bf16(A2l[mf2], bh.s8, acc2[mf2][nf], 0, 0, 0);
                acc2[mf2][nf] = __builtin_amdgcn_mfma_f32_16x16x32_bf16(A2h[mf2], bl.s8, acc2[mf2][nf], 0, 0, 0);
            }
        }
    }

    // ---- epilogue: y = s + x_center (re-read from global; same frag address as Y write) ----
    float bo2[2][4];
    #pragma unroll
    for (int mf2 = 0; mf2 < 2; mf2++)
        #pragma unroll
        for (int r = 0; r < 4; r++) bo2[mf2][r] = skb[(2 * wid + mf2) * 16 + cb + r];
    #pragma unroll
    for (int nf = 0; nf < 4; nf++) {
        size_t gi = fidx(n, tb0 + nf, wid, lane);
        U4S8 xh, xl, oh, ol;
        xh.v = Xh[gi]; xl.v = Xl[gi];
        #pragma unroll
        for (int j = 0; j < 8; j++) {
            int mf2 = j >> 2, r = j & 3;
            float xin = b2f(xh.us[j]) + b2f(xl.us[j]);
            float sv = acc2[mf2][nf][r] + bo2[mf2][r];
            unsigned short hi, lo; bsplit(sv + xin, hi, lo);
            oh.us[j] = hi; ol.us[j] = lo;
        }
        Yh[gi] = oh.v; Yl[gi] = ol.v;
    }
}

// ======================= fused output stack =======================
__global__ __launch_bounds__(256, 2)
void os_fused(const uint4* __restrict__ Fh, const uint4* __restrict__ Fl,
              const uint4* __restrict__ Ih, const uint4* __restrict__ Il,
              const unsigned short* __restrict__ Opk1, const float* __restrict__ o1b,
              const unsigned short* __restrict__ Opk2, const float* __restrict__ o2b,
              const float* __restrict__ o3w, const float* __restrict__ o3b,
              float* __restrict__ out)
{
    __shared__ __align__(16) uint4 SA[2048];
    __shared__ __align__(16) uint4 SB[2048];
    const int n = blockIdx.y, tb0 = blockIdx.x * 4, t0 = tb0 * 16;
    const int tid = threadIdx.x, lane = tid & 63, wid = tid >> 6;
    const int tl = lane & 15, cb = 4 * (lane >> 4);
    const f32x4 z4 = {0.f, 0.f, 0.f, 0.f};
    char* ldsA = (char*)SA;

    for (int j = tid; j < 1024; j += 256) {
        int l = j & 63, c = (j >> 6) & 3, nf = j >> 8;
        size_t gi = fidx(n, tb0 + nf, c, l);
        U4S8 fh, fl, ih, il, ho, lo_;
        fh.v = Fh[gi]; fl.v = Fl[gi]; ih.v = Ih[gi]; il.v = Il[gi];
        #pragma unroll
        for (int e = 0; e < 8; e++) {
            float d = (b2f(fh.us[e]) + b2f(fl.us[e])) - (b2f(ih.us[e]) + b2f(il.us[e]));
            d = fmaxf(d, 0.f);
            unsigned short hi, lo; bsplit(d, hi, lo);
            ho.us[e] = hi; lo_.us[e] = lo;
        }
        SA[j] = ho.v; SA[1024 + j] = lo_.v;
    }
    __syncthreads();

    {
        f32x4 acc[2][4];
        #pragma unroll
        for (int mf2 = 0; mf2 < 2; mf2++)
            #pragma unroll
            for (int nf = 0; nf < 4; nf++) acc[mf2][nf] = z4;
        const short8* op = (const short8*)Opk1;
        #pragma unroll
        for (int c = 0; c < 4; c++) {
            short8 Ah[2], Al[2];
            #pragma unroll
            for (int mf2 = 0; mf2 < 2; mf2++) {
                int ib = (c * 8 + 2 * wid + mf2) * 128 + lane;
                Ah[mf2] = op[ib]; Al[mf2] = op[ib + 64];
            }
            #pragma unroll
            for (int nf = 0; nf < 4; nf++) {
                U4S8 bh, bl;
                bh.v = SA[(nf * 4 + c) * 64 + lane];
                bl.v = SA[1024 + (nf * 4 + c) * 64 + lane];
                #pragma unroll
                for (int mf2 = 0; mf2 < 2; mf2++) {
                    acc[mf2][nf] = __builtin_amdgcn_mfma_f32_16x16x32_bf16(Ah[mf2], bh.s8, acc[mf2][nf], 0, 0, 0);
                    acc[mf2][nf] = __builtin_amdgcn_mfma_f32_16x16x32_bf16(Al[mf2], bh.s8, acc[mf2][nf], 0, 0, 0);
                    acc[mf2][nf] = __builtin_amdgcn_mfma_f32_16x16x32_bf16(Ah[mf2], bl.s8, acc[mf2][nf], 0, 0, 0);
                }
            }
        }
        #pragma unroll
        for (int nf = 0; nf < 4; nf++) {
            U4S8 h4, l4;
            #pragma unroll
            for (int mf2 = 0; mf2 < 2; mf2++)
                #pragma unroll
                for (int r = 0; r < 4; r++) {
                    float v = fmaxf(acc[mf2][nf][r] + o1b[(2 * wid + mf2) * 16 + cb + r], 0.f);
                    unsigned short hi, lo; bsplit(v, hi, lo);
                    h4.us[mf2 * 4 + r] = hi; l4.us[mf2 * 4 + r] = lo;
                }
            SB[(nf * 4 + wid) * 64 + lane] = h4.v;
            SB[1024 + (nf * 4 + wid) * 64 + lane] = l4.v;
        }
    }
    __syncthreads();

    {
        f32x4 acc[2][4];
        #pragma unroll
        for (int mf2 = 0; mf2 < 2; mf2++)
            #pragma unroll
            for (int nf = 0; nf < 4; nf++) acc[mf2][nf] = z4;
        const short8* op = (const short8*)Opk2;
        #pragma unroll
        for (int c = 0; c < 4; c++) {
            short8 Ah[2], Al[2];
            #pragma unroll
            for (int mf2 = 0; mf2 < 2; mf2++) {
                int ib = (c * 8 + 2 * wid + mf2) * 128 + lane;
                Ah[mf2] = op[ib]; Al[mf2] = op[ib + 64];
            }
            #pragma unroll
            for (int nf = 0; nf < 4; nf++) {
                U4S8 bh, bl;
                bh.v = SB[(nf * 4 + c) * 64 + lane];
                bl.v = SB[1024 + (nf * 4 + c) * 64 + lane];
                #pragma unroll
                for (int mf2 = 0; mf2 < 2; mf2++) {
                    acc[mf2][nf] = __builtin_amdgcn_mfma_f32_16x16x32_bf16(Ah[mf2], bh.s8, acc[mf2][nf], 0, 0, 0);
                    acc[mf2][nf] = __builtin_amdgcn_mfma_f32_16x16x32_bf16(Al[mf2], bh.s8, acc[mf2][nf], 0, 0, 0);
                    acc[mf2][nf] = __builtin_amdgcn_mfma_f32_16x16x32_bf16(Ah[mf2], bl.s8, acc[mf2][nf], 0, 0, 0);
                }
            }
        }
        __syncthreads();
        #pragma unroll
        for (int mf2 = 0; mf2 < 2; mf2++) {
            const int ch0 = (2 * wid + mf2) * 16 + cb;
            #pragma unroll
            for (int nf = 0; nf < 4; nf++) {
                int row = nf * 16 + tl, swz = (row & 7) << 4;
                float4 v;
                v.x = fmaxf(acc[mf2][nf][0] + o2b[ch0 + 0], 0.f);
                v.y = fmaxf(acc[mf2][nf][1] + o2b[ch0 + 1], 0.f);
                v.z = fmaxf(acc[mf2][nf][2] + o2b[ch0 + 2], 0.f);
                v.w = fmaxf(acc[mf2][nf][3] + o2b[ch0 + 3], 0.f);
                *(float4*)(ldsA + row * 512 + ((ch0 * 4) ^ swz)) = v;
            }
        }
    }
    __syncthreads();

    {
        const int t_loc = tid >> 2, qq = tid & 3;
        const int row = t_loc, swz = (row & 7) << 4;
        float a = 0.f;
        #pragma unroll
        for (int cc = 0; cc < 8; cc++) {
            int ch = qq * 32 + cc * 4;
            float4 v = *(const float4*)(ldsA + row * 512 + ((ch * 4) ^ swz));
            a += o3w[ch] * v.x + o3w[ch + 1] * v.y + o3w[ch + 2] * v.z + o3w[ch + 3] * v.w;
        }
        a += __shfl_xor(a, 1);
        a += __shfl_xor(a, 2);
        if (qq == 0) out[(size_t)n * T_LEN + t0 + t_loc] = tanhf(a + o3b[0]);
    }
}

// ======================= launch =======================
extern "C" void kernel_launch(void* const* d_in, const int* in_sizes, int n_in,
                              void* d_out, int out_size, void* d_ws, size_t ws_size,
                              hipStream_t stream)
{
    (void)in_sizes; (void)n_in; (void)out_size; (void)ws_size;
    const float* mel    = (const float*)d_in[0];
    const float* in_w   = (const float*)d_in[1];
    const float* in_b   = (const float*)d_in[2];
    const float* pre_w  = (const float*)d_in[3];
    const float* pre_b  = (const float*)d_in[4];
    const float* up1_w  = (const float*)d_in[5];
    const float* up1_b  = (const float*)d_in[6];
    const float* up2_w  = (const float*)d_in[7];
    const float* up2_b  = (const float*)d_in[8];
    const float* wn_wsp = (const float*)d_in[9];
    const float* wn_bs  = (const float*)d_in[10];
    const float* sk_wsp = (const float*)d_in[11];
    const float* sk_bs  = (const float*)d_in[12];
    const float* o1w = (const float*)d_in[13];
    const float* o1b = (const float*)d_in[14];
    const float* o2w = (const float*)d_in[15];
    const float* o2b = (const float*)d_in[16];
    const float* o3w = (const float*)d_in[17];
    const float* o3b = (const float*)d_in[18];

    // each bf16 plane: 8,388,608 elems = 16,777,216 BYTES
    char* base = (char*)d_ws;
    uint4* XAh = (uint4*)(base);
    uint4* XAl = (uint4*)(base + 16777216);
    uint4* XBh = (uint4*)(base + 33554432);
    uint4* XBl = (uint4*)(base + 50331648);
    uint4* XCh = (uint4*)(base + 67108864);
    uint4* XCl = (uint4*)(base + 83886080);
    unsigned short* Apk = (unsigned short*)(base + 100663296);   // 11,796,480 B
    unsigned short* Spk = (unsigned short*)(base + 112459776);   //  1,966,080 B
    unsigned short* Opk1 = (unsigned short*)(base + 114425856);  //     65,536 B
    unsigned short* Opk2 = (unsigned short*)(base + 114491392);  //     65,536 B
    float* a64   = (float*)(base + 114556928);
    float* b64   = (float*)(base + 114688000);
    float* x256  = (float*)(base + 114819072);
    float* x1024 = (float*)(base + 115343360);

    prep_w3<<<488, 256, 0, stream>>>(wn_wsp, sk_wsp, o1w, o2w, Apk, Spk, Opk1, Opk2);

    fe_in<<<dim3(64, 4), 128, 0, stream>>>(mel, in_w, in_b, a64);
    fe_pre<<<dim3(64, 4), 128, 0, stream>>>(a64, b64, pre_w + 0 * 49152, pre_b + 0 * 128, 1);
    fe_pre<<<dim3(64, 4), 128, 0, stream>>>(b64, a64, pre_w + 1 * 49152, pre_b + 1 * 128, 2);
    fe_pre<<<dim3(64, 4), 128, 0, stream>>>(a64, b64, pre_w + 2 * 49152, pre_b + 2 * 128, 4);
    fe_pre<<<dim3(64, 4), 128, 0, stream>>>(b64, a64, pre_w + 3 * 49152, pre_b + 3 * 128, 8);
    fe_pre<<<dim3(64, 4), 128, 0, stream>>>(a64, b64, pre_w + 4 * 49152, pre_b + 4 * 128, 16);
    fe_up3<<<dim3(4, 4), 256, 0, stream>>>(b64, x256, up1_w, up1_b, 64);
    fe_up3<<<dim3(16, 4), 256, 0, stream>>>(x256, x1024, up2_w, up2_b, 256);
    fe_repeat_f<<<dim3(16, 4), 256, 0, stream>>>(x1024, XAh, XAl);

    for (int li = 0; li < 30; li++) {
        int d = 1 << (li % 10);
        const uint4 *ih, *il; uint4 *oh, *ol;
        if (li == 0)      { ih = XAh; il = XAl; oh = XBh; ol = XBl; }
        else if (li & 1)  { ih = XBh; il = XBl; oh = XCh; ol = XCl; }
        else              { ih = XCh; il = XCl; oh = XBh; ol = XBl; }
        wn_layer<<<dim3(T_LEN / 64, 4), 256, 0, stream>>>(
            ih, il, oh, ol,
            Apk + (size_t)li * 196608, wn_bs + li * 256,
            Spk + (size_t)li * 32768, sk_bs + li * 128, d);
    }

    // skips = x_final - x_init
    os_fused<<<dim3(T_LEN / 64, 4), 256, 0, stream>>>(
        XCh, XCl, XAh, XAl, Opk1, o1b, Opk2, o2b, o3w, o3b, (float*)d_out);
}